// Round 8
// baseline (385.197 us; speedup 1.0000x reference)
//
#include <hip/hip_runtime.h>
#include <hip/hip_bf16.h>

// Fused two-stage head-softmax attention, B=8 H=8 N=1024 D=128, f32 in/out.
// softmax is over the HEAD axis (pointwise per (n,m)) -> no online softmax;
// block = (batch, 32-row n-tile) x all 8 heads fuses both stages.
// Correctness-anchor build: V^T global prepass (no ds_read_b64_tr_b16),
// race-hardened barriers (memory-clobber asm both sides of s_barrier),
// f16 MFMA inputs, f32 softmax/accum.

#define BB 8
#define HH 8
#define NN 1024
#define DD 128
#define TOT (BB*HH*NN*DD)
#define RSCALE 0.08838834764831845f  // 1/sqrt(128)

typedef __attribute__((ext_vector_type(8))) short u16x8;
typedef __attribute__((ext_vector_type(8))) _Float16 f16x8;
typedef __attribute__((ext_vector_type(4))) float f32x4;
typedef __attribute__((ext_vector_type(4))) int i32x4;

__device__ __forceinline__ unsigned short f2h(float x){
  _Float16 h = (_Float16)x;
  return __builtin_bit_cast(unsigned short, h);
}
__device__ __forceinline__ f32x4 mfma16(u16x8 a, u16x8 b, f32x4 c){
  return __builtin_amdgcn_mfma_f32_16x16x32_f16(
      __builtin_bit_cast(f16x8, a), __builtin_bit_cast(f16x8, b), c, 0, 0, 0);
}
// Race-hardened barrier: s_barrier intrinsic is IntrNoMem, so ordinary LDS
// loads can hoist above it. Memory-clobber asm on BOTH sides pins every LDS
// access inside its phase. vmcnt deliberately NOT drained (K/V prefetch
// stays in flight across barriers).
#define BARRIER() do { asm volatile("s_waitcnt lgkmcnt(0)" ::: "memory"); \
                       __builtin_amdgcn_s_barrier(); \
                       asm volatile("" ::: "memory"); } while(0)

// ---------------- prepass 1: f32 -> f16 straight copy ----------------
__global__ void convert_kernel(const float* __restrict__ sal, const float* __restrict__ si,
                               unsigned short* __restrict__ sal_h, unsigned short* __restrict__ si_h){
  int idx = blockIdx.x * blockDim.x + threadIdx.x;
  const int per = TOT / 8;
  const float* src; unsigned short* dst; int o;
  if (idx < per){ src = sal; dst = sal_h; o = idx; } else { src = si; dst = si_h; o = idx - per; }
  const float4* s4 = (const float4*)(src + (size_t)o * 8);
  float4 a = s4[0], c = s4[1];
  unsigned short r0 = f2h(a.x), r1 = f2h(a.y), r2 = f2h(a.z), r3 = f2h(a.w);
  unsigned short r4 = f2h(c.x), r5 = f2h(c.y), r6 = f2h(c.z), r7 = f2h(c.w);
  int i0 = (r1 << 16) | r0, i1 = (r3 << 16) | r2, i2 = (r5 << 16) | r4, i3 = (r7 << 16) | r6;
  i32x4 v = { i0, i1, i2, i3 };
  *(i32x4*)(dst + (size_t)o * 8) = v;
}

// ---------------- prepass 2: f32 [n][d] -> f16 transposed [d][n] ----------------
__global__ void transpose_kernel(const float* __restrict__ sal, const float* __restrict__ si,
                                 unsigned short* __restrict__ sal_t, unsigned short* __restrict__ si_t){
  __shared__ unsigned short tile[32][33];
  int bh = blockIdx.y;                    // 0..63  (b*8+h)
  const float* src = blockIdx.z ? si : sal;
  unsigned short* dst = blockIdx.z ? si_t : sal_t;
  int n0 = (blockIdx.x & 31) * 32;
  int d0 = (blockIdx.x >> 5) * 32;
  const float* sbase = src + (size_t)bh * NN * DD;
  unsigned short* dbase = dst + (size_t)bh * DD * NN;
#pragma unroll
  for (int i = 0; i < 4; i++){
    int idx = threadIdx.x + i * 256; int r = idx >> 5, c = idx & 31;
    tile[r][c] = f2h(sbase[(size_t)(n0 + r) * DD + d0 + c]);
  }
  __syncthreads();
#pragma unroll
  for (int i = 0; i < 4; i++){
    int idx = threadIdx.x + i * 256; int dr = idx >> 5, nc = idx & 31;
    dbase[(size_t)(d0 + dr) * NN + n0 + nc] = tile[nc][dr];
  }
}

// ---------------- main fused kernel ----------------
// LDS (48 KB):
//  Eb @ 0     : 32 KB f32 [h][n 32][m_sw 32], m_sw = m ^ ((n>>2)&1)<<4 ^ ((n>>3)&3)<<2
//               (also reused as the stage-transition buffer, 4 KB/head)
//  At @ 32768 : 16 KB f16 [h][n 32][blk_sw 4][m&7], blk_sw = (m>>3) ^ (n&3)

__device__ __forceinline__ void kload(u16x8 (&buf)[2][4], const unsigned short* kbase, int mB){
#pragma unroll
  for (int mt = 0; mt < 2; mt++)
#pragma unroll
    for (int kc = 0; kc < 4; kc++)
      buf[mt][kc] = *(const u16x8*)(kbase + (mB + mt*16)*128 + kc*32);
}

__device__ __forceinline__ void step(char* lds,
    const unsigned short* kbase, const unsigned short* vtbase, int t,
    u16x8 (&q)[2][4], u16x8 (&cur)[2][4], u16x8 (&nxt)[2][4],
    f32x4 (&acc)[2][8],
    int h, int lr, int lg, int tid){
  // ---- QK^T (Q, K both in regs) ----
  f32x4 e[2][2];
#pragma unroll
  for (int nt = 0; nt < 2; nt++)
#pragma unroll
    for (int mt = 0; mt < 2; mt++) e[nt][mt] = (f32x4){0,0,0,0};
#pragma unroll
  for (int kc = 0; kc < 4; kc++)
#pragma unroll
    for (int nt = 0; nt < 2; nt++)
#pragma unroll
      for (int mt = 0; mt < 2; mt++)
        e[nt][mt] = mfma16(q[nt][kc], cur[mt][kc], e[nt][mt]);
  // ---- prefetch next K tile (global -> regs) ----
  kload(nxt, kbase, ((t+1)&31)*32);
  // ---- load current V^T B-frags (global -> regs; used after 2 barriers) ----
  u16x8 v[8];
  const int mB = t*32;
#pragma unroll
  for (int dt = 0; dt < 8; dt++)
    v[dt] = *(const u16x8*)(vtbase + (size_t)(dt*16)*1024 + mB);
  // ---- write energies to per-head planes (even-bank swizzle) ----
  // n = nt*16+lg*4+r : (n>>2)&1 = lg&1 ; (n>>3)&3 = (nt*2+(lg>>1))&3
#pragma unroll
  for (int nt = 0; nt < 2; nt++){
    const unsigned swz = (unsigned)((((unsigned)lg&1u)<<4) | ((((unsigned)nt*2u + ((unsigned)lg>>1))&3u)<<2));
#pragma unroll
    for (int mt = 0; mt < 2; mt++)
#pragma unroll
      for (int r = 0; r < 4; r++){
        unsigned n = (unsigned)(nt*16 + lg*4 + r), m = (unsigned)(mt*16 + lr);
        unsigned msw = m ^ swz;
        *(float*)(lds + (h<<12) + (n<<7) + (msw<<2)) = e[nt][mt][r] * RSCALE;
      }
  }
  BARRIER();
  // ---- softmax over the 8 heads, 2 (n,m) points per thread ----
#pragma unroll
  for (int pp = 0; pp < 2; pp++){
    int p = tid + pp*512;
    unsigned n = (unsigned)p >> 5, m = (unsigned)p & 31;
    unsigned msw = m ^ (((n>>2)&1u)<<4) ^ (((n>>3)&3u)<<2);
    float eh[8];
#pragma unroll
    for (int h2 = 0; h2 < 8; h2++)
      eh[h2] = *(const float*)(lds + (h2<<12) + (n<<7) + (msw<<2));
    float mx = fmaxf(fmaxf(fmaxf(eh[0],eh[1]), fmaxf(eh[2],eh[3])),
                     fmaxf(fmaxf(eh[4],eh[5]), fmaxf(eh[6],eh[7])));
    float pr[8]; float s = 0.f;
#pragma unroll
    for (int h2 = 0; h2 < 8; h2++){ pr[h2] = __expf(eh[h2]-mx); s += pr[h2]; }
    float inv = 1.0f / s;
    unsigned abase = 32768u + (n<<6) + ((((m>>3) ^ (n&3))&3u)<<4) + ((m&7u)<<1);
#pragma unroll
    for (int h2 = 0; h2 < 8; h2++)
      *(unsigned short*)(lds + abase + (h2<<11)) = f2h(pr[h2]*inv);
  }
  BARRIER();
  // ---- PV: A = attention rows (swizzled 16B blocks), B = V^T frags ----
  unsigned pab = 32768u + ((unsigned)h<<11) + (((unsigned)(lg ^ (lr&3))&3u)<<4);
  u16x8 pa0 = *(const u16x8*)(lds + pab + ((unsigned)lr<<6));
  u16x8 pa1 = *(const u16x8*)(lds + pab + ((unsigned)(lr+16)<<6));
#pragma unroll
  for (int dt = 0; dt < 8; dt++){
    acc[0][dt] = mfma16(pa0, v[dt], acc[0][dt]);
    acc[1][dt] = mfma16(pa1, v[dt], acc[1][dt]);
  }
  BARRIER();
}

__global__ __launch_bounds__(512, 1)
void attn_kernel(const float* __restrict__ sal_f,
                 const unsigned short* __restrict__ sal_h,
                 const unsigned short* __restrict__ si_h,
                 const unsigned short* __restrict__ sal_t,
                 const unsigned short* __restrict__ si_t,
                 float* __restrict__ out){
  extern __shared__ char lds[];
  const int b  = blockIdx.x & 7;           // batch -> XCD affine
  const int n0 = (blockIdx.x >> 3) << 5;   // 32-row n-tile
  const int tid = threadIdx.x;
  const int h  = tid >> 6;                 // wave = head
  const int l  = tid & 63;
  const int lr = l & 15, lg = l >> 4;
  const int bh = b*HH + h;

  u16x8 q[2][4], kA[2][4], kB[2][4];
  f32x4 acc[2][8];

  // stage-0 Q = si rows (A-frag: row=lr, k = kc*32 + lg*8 + j)
  {
    const unsigned short* qb = si_h + ((size_t)bh*1024 + n0 + lr)*128 + lg*8;
#pragma unroll
    for (int nt = 0; nt < 2; nt++)
#pragma unroll
      for (int kc = 0; kc < 4; kc++)
        q[nt][kc] = *(const u16x8*)(qb + nt*16*128 + kc*32);
  }

#pragma unroll 1
  for (int stage = 0; stage < 2; stage++){
    const unsigned short* kvb = stage ? sal_h : si_h;
    const unsigned short* kvt = stage ? sal_t : si_t;
    const unsigned short* kbase  = kvb + ((size_t)bh*1024 + lr)*128 + lg*8;
    const unsigned short* vtbase = kvt + ((size_t)bh*128 + lr)*1024 + lg*8;
#pragma unroll
    for (int nt = 0; nt < 2; nt++)
#pragma unroll
      for (int dt = 0; dt < 8; dt++) acc[nt][dt] = (f32x4){0,0,0,0};
    kload(kA, kbase, 0);
#pragma unroll 1
    for (int t = 0; t < 32; t += 2){
      step(lds, kbase, vtbase, t,   q, kA, kB, acc, h, lr, lg, tid);
      step(lds, kbase, vtbase, t+1, q, kB, kA, acc, h, lr, lg, tid);
    }
    if (stage == 0){
      // transition: x_self (C-frag) -> LDS (Eb region, 4KB/head) -> Q A-frags
#pragma unroll
      for (int nt = 0; nt < 2; nt++){
#pragma unroll
        for (int dt = 0; dt < 8; dt++)
#pragma unroll
          for (int r = 0; r < 4; r++){
            int n = lg*4 + r, d = dt*16 + lr;
            unsigned a = (unsigned)(((h<<12) + (n<<8) + (d<<1)) ^ ((n&7)<<4));
            *(unsigned short*)(lds + a) = f2h(acc[nt][dt][r]);
          }
        __syncthreads();
#pragma unroll
        for (int kc = 0; kc < 4; kc++){
          unsigned a = (unsigned)(((h<<12) + (lr<<8) + (kc<<6) + (lg<<4)) ^ ((lr&7)<<4));
          q[nt][kc] = *(const u16x8*)(lds + a);
        }
        __syncthreads();
      }
    }
  }

  // epilogue: out = sal + x
#pragma unroll
  for (int nt = 0; nt < 2; nt++)
#pragma unroll
    for (int dt = 0; dt < 8; dt++)
#pragma unroll
      for (int r = 0; r < 4; r++){
        int n = n0 + nt*16 + lg*4 + r, d = dt*16 + lr;
        size_t g = ((size_t)bh*1024 + n)*128 + d;
        out[g] = sal_f[g] + acc[nt][dt][r];
      }
}

extern "C" void kernel_launch(void* const* d_in, const int* in_sizes, int n_in,
                              void* d_out, int out_size, void* d_ws, size_t ws_size,
                              hipStream_t stream){
  const float* sal = (const float*)d_in[0];
  const float* si  = (const float*)d_in[1];
  float* out = (float*)d_out;
  unsigned short* sal_h = (unsigned short*)d_ws;
  unsigned short* si_h  = sal_h + (size_t)TOT;
  unsigned short* sal_t = sal_h + 2 * (size_t)TOT;
  unsigned short* si_t  = sal_h + 3 * (size_t)TOT;

  convert_kernel<<<(2 * TOT / 8) / 256, 256, 0, stream>>>(sal, si, sal_h, si_h);
  transpose_kernel<<<dim3(128, 64, 2), 256, 0, stream>>>(sal, si, sal_t, si_t);

  attn_kernel<<<256, 512, 49152, stream>>>(sal, sal_h, si_h, sal_t, si_t, out);
}